// Round 18
// baseline (112.799 us; speedup 1.0000x reference)
//
#include <hip/hip_runtime.h>

// Attention_Layer: scores=d@e^T -> softmax -> value=attn@e -> tanh([value,d]@W+b)
// B=8 TE=4096 TD=1024 H=256 NH=256, f32 in/out.
// Round 18: round-17 (2 q-groups/wave, halved LDS reads) with the fp16
// underflow bug fixed: PER-GROUP running max m0/m1 (shared-m underflowed the
// weaker row's unnormalized fp16 pacc to 0 -> O(1) combine error). 4 shfl/pair.
// 4 waves x 32q, 1 wave/SIMD, ~370 VGPR legal. Staging/swizzles/prep/dense2
// verbatim from round 16 (best passing: 92.7us).

#define B_ 8
#define TE_ 4096
#define TD_ 1024
#define H_ 256
#define NS_ 4
#define CHUNK_ (TE_ / NS_)   // 1024
#define NIT_ (CHUNK_ / 32)   // 32 tiles -> 16 pairs
#define NROW_ (B_ * TD_)     // 8192

typedef __attribute__((ext_vector_type(8))) short s16x8;
typedef __attribute__((ext_vector_type(8))) _Float16 h16x8;
typedef __attribute__((ext_vector_type(4))) float fx4;
typedef __attribute__((ext_vector_type(16))) float fx16;
typedef __attribute__((ext_vector_type(4))) unsigned short u16x4;

__device__ __forceinline__ h16x8 as_h(s16x8 v) {
  union { s16x8 s; h16x8 h; } u; u.s = v; return u.h;
}
#define MFMA(a, b, c) __builtin_amdgcn_mfma_f32_16x16x32_f16(as_h(a), as_h(b), c, 0, 0, 0)
#define MFMA32(a, b, c) __builtin_amdgcn_mfma_f32_32x32x16_f16(as_h(a), as_h(b), c, 0, 0, 0)

__device__ __forceinline__ unsigned short f2h(float x) {
  const _Float16 h = (_Float16)x;    // RNE
  union { _Float16 h; unsigned short s; } u; u.h = h; return u.s;
}
__device__ __forceinline__ float h2f(unsigned short s) {
  union { unsigned short s; _Float16 h; } u; u.s = s; return (float)u.h;
}
__device__ __forceinline__ unsigned pk2h(float f0, float f1) {
  return (unsigned)f2h(f0) | ((unsigned)f2h(f1) << 16);
}
__device__ __forceinline__ void gload_lds16(const void* g, void* l) {
  __builtin_amdgcn_global_load_lds(
      (const __attribute__((address_space(1))) void*)g,
      (__attribute__((address_space(3))) void*)l, 16, 0, 0);
}

// ---------------- prep: e -> eh fp16 [b][TE][H], eT fp16 [b][H][TE];
//                  W -> WT fp16 [256n][512k]   (verbatim)
__global__ __launch_bounds__(256) void prep(const float* __restrict__ e,
                                            const float* __restrict__ W,
                                            unsigned short* __restrict__ eh,
                                            unsigned short* __restrict__ eT,
                                            unsigned short* __restrict__ WT) {
  __shared__ unsigned short lt[64][65];
  __shared__ float wl[32][33];
  const int bid = blockIdx.x;
  const int tid = threadIdx.x;
  if (bid < 2048) {                   // e part: 8 * 64 * 4 tiles
    const int b = bid >> 8;
    const int s0 = ((bid >> 2) & 63) * 64;
    const int h0 = (bid & 3) * 64;
#pragma unroll
    for (int i = 0; i < 4; ++i) {
      const int row = (tid >> 4) + 16 * i;
      const int col = (tid & 15) * 4;
      const size_t go = (((size_t)b * TE_) + s0 + row) * H_ + h0 + col;
      const fx4 v = *(const fx4*)&e[go];
      u16x4 hv;
#pragma unroll
      for (int j = 0; j < 4; ++j) {
        const unsigned short hb = f2h(v[j]);
        hv[j] = hb;
        lt[row][col + j] = hb;
      }
      *(u16x4*)&eh[go] = hv;
    }
    __syncthreads();
#pragma unroll
    for (int i = 0; i < 2; ++i) {
      const int idx = tid + 256 * i;
      const int hh = idx >> 3;
      const int sc = (idx & 7) * 8;
      s16x8 v;
#pragma unroll
      for (int j = 0; j < 8; ++j) v[j] = (short)lt[sc + j][hh];
      *(s16x8*)&eT[(((size_t)b * H_) + h0 + hh) * TE_ + s0 + sc] = v;
    }
  } else {                            // W part: 128 tiles of 32x32
    const int tb = bid - 2048;
    const int k0 = (tb >> 3) * 32, n0 = (tb & 7) * 32;
    const int r = tid >> 3, c4 = (tid & 7) * 4;
    const fx4 v = *(const fx4*)&W[(size_t)(k0 + r) * 256 + n0 + c4];
#pragma unroll
    for (int j = 0; j < 4; ++j) wl[r][c4 + j] = v[j];
    __syncthreads();
    u16x4 o;
#pragma unroll
    for (int j = 0; j < 4; ++j) o[j] = f2h(wl[c4 + j][r]);
    *(u16x4*)&WT[(size_t)(n0 + r) * 512 + k0 + c4] = o;
  }
}

// ---------------- flash18: 256 blocks = b(8)|qb(8)|ns(4); 4 waves x 32 q
__global__ __launch_bounds__(256, 1) void flash18(
    const unsigned short* __restrict__ eh_g, const unsigned short* __restrict__ eT_g,
    const float* __restrict__ dmat,
    unsigned short* __restrict__ pacc, float* __restrict__ pm,
    float* __restrict__ pl) {
  const int bid = blockIdx.x;
  const int ns = bid & 3;             // 4-way KV split (proven mapping)
  const int qb = (bid >> 2) & 7;
  const int b = bid >> 5;
  const int tid = threadIdx.x;
  const int w = tid >> 6;             // 4 waves
  const int lane = tid & 63;
  const int g = lane >> 4, c = lane & 15;
  const int qrow0 = qb * 128 + w * 32 + c;        // group 0
  const int qrow1 = qrow0 + 16;                   // group 1

  __shared__ uint4 smem[4][2][1024];  // 128 KB: 4-deep x {eh, eT}

  // ---- staging sources; sigma(s) = (s&3)|(((s>>3)&1)<<2)
  const unsigned short* pEh[4];
  const unsigned short* pEt[4];
  {
    const size_t ebase = ((size_t)b * TE_ + ns * CHUNK_) * H_;
    const size_t tbase = (size_t)b * H_ * TE_ + ns * CHUNK_;
#pragma unroll
    for (int i = 0; i < 4; ++i) {
      const int L = tid + 256 * i;
      const int s = L >> 5, ch = L & 31;
      const int sg = (s & 3) | (((s >> 3) & 1) << 2);
      pEh[i] = eh_g + ebase + s * H_ + (ch ^ sg) * 8;
      const int h2 = (L >> 6) * 16 + (L & 15), sc = ((L >> 4) & 3) * 8;
      pEt[i] = eT_g + tbase + (size_t)h2 * TE_ + sc;
    }
  }
  auto STAGE = [&](int buf) {
    uint4* ehb = smem[buf][0];
    uint4* etb = smem[buf][1];
#pragma unroll
    for (int i = 0; i < 4; ++i) {
      gload_lds16(pEh[i], &ehb[tid + 256 * i]);
      gload_lds16(pEt[i], &etb[tid + 256 * i]);
      pEh[i] += 32 * H_;              // s += 32
      pEt[i] += 32;                   // s += 32 (inner dim)
    }
  };

  STAGE(0);                           // tiles 0,1 in flight during d-preload
  STAGE(1);

  // ---- d B-frags hi/lo fp16 in registers, both q-groups (d exact: dh + dl)
  s16x8 bd_h[2][8], bd_l[2][8];
#pragma unroll
  for (int grp = 0; grp < 2; ++grp) {
    const float* dr = dmat + ((size_t)b * TD_ + (grp ? qrow1 : qrow0)) * H_;
#pragma unroll
    for (int kk = 0; kk < 8; ++kk) {
      const fx4 x0 = *(const fx4*)&dr[kk * 32 + g * 8];
      const fx4 x1 = *(const fx4*)&dr[kk * 32 + g * 8 + 4];
      s16x8 hh, ll;
#pragma unroll
      for (int j = 0; j < 4; ++j) {
        unsigned short hb = f2h(x0[j]);
        hh[j] = (short)hb; ll[j] = (short)f2h(x0[j] - h2f(hb));
        hb = f2h(x1[j]);
        hh[4 + j] = (short)hb; ll[4 + j] = (short)f2h(x1[j] - h2f(hb));
      }
      bd_h[grp][kk] = hh; bd_l[grp][kk] = ll;
    }
  }

  fx4 acc0[16], acc1[16];
#pragma unroll
  for (int nt = 0; nt < 16; ++nt) {
    acc0[nt] = (fx4){0.f, 0.f, 0.f, 0.f};
    acc1[nt] = (fx4){0.f, 0.f, 0.f, 0.f};
  }
  float m0 = -__builtin_inff(), m1 = -__builtin_inff();   // PER-GROUP maxima
  float l0 = 0.f, l1 = 0.f;
  const int xr = (c & 3) | (((c >> 2) & 1) << 2);   // = sigma(rho) = sigma(rho+4)
  const int rho = (c & 3) + (c >> 2) * 8;           // s-row permutation

  __syncthreads();                    // tiles 0,1 resident

  for (int p = 0; p < NIT_ / 2; ++p) {
    const int bufA = (p & 1) << 1;
    const int bufB = bufA + 1;
    if (p + 1 < NIT_ / 2) {           // prefetch next pair (drained at barrier)
      STAGE(bufA ^ 2);
      STAGE(bufB ^ 2);
    }
    const uint4* ehbA = smem[bufA][0];
    const uint4* etbA = smem[bufA][1];
    const uint4* ehbB = smem[bufB][0];
    const uint4* etbB = smem[bufB][1];

    // ---- QK^T both tiles x both groups; A-frags read ONCE per (kk, tile)
    fx4 sA0g0 = (fx4){0.f,0.f,0.f,0.f}, sA1g0 = (fx4){0.f,0.f,0.f,0.f};
    fx4 sB0g0 = (fx4){0.f,0.f,0.f,0.f}, sB1g0 = (fx4){0.f,0.f,0.f,0.f};
    fx4 sA0g1 = (fx4){0.f,0.f,0.f,0.f}, sA1g1 = (fx4){0.f,0.f,0.f,0.f};
    fx4 sB0g1 = (fx4){0.f,0.f,0.f,0.f}, sB1g1 = (fx4){0.f,0.f,0.f,0.f};
#pragma unroll
    for (int kk = 0; kk < 8; ++kk) {
      const int sl = (kk * 4 + g) ^ xr;
      const s16x8 aA0 = *(const s16x8*)&ehbA[rho * 32 + sl];
      const s16x8 aA1 = *(const s16x8*)&ehbA[(rho + 4) * 32 + sl];
      const s16x8 aB0 = *(const s16x8*)&ehbB[rho * 32 + sl];
      const s16x8 aB1 = *(const s16x8*)&ehbB[(rho + 4) * 32 + sl];
      sA0g0 = MFMA(aA0, bd_h[0][kk], sA0g0);
      sA0g0 = MFMA(aA0, bd_l[0][kk], sA0g0);
      sA0g1 = MFMA(aA0, bd_h[1][kk], sA0g1);
      sA0g1 = MFMA(aA0, bd_l[1][kk], sA0g1);
      sA1g0 = MFMA(aA1, bd_h[0][kk], sA1g0);
      sA1g0 = MFMA(aA1, bd_l[0][kk], sA1g0);
      sA1g1 = MFMA(aA1, bd_h[1][kk], sA1g1);
      sA1g1 = MFMA(aA1, bd_l[1][kk], sA1g1);
      sB0g0 = MFMA(aB0, bd_h[0][kk], sB0g0);
      sB0g0 = MFMA(aB0, bd_l[0][kk], sB0g0);
      sB0g1 = MFMA(aB0, bd_h[1][kk], sB0g1);
      sB0g1 = MFMA(aB0, bd_l[1][kk], sB0g1);
      sB1g0 = MFMA(aB1, bd_h[0][kk], sB1g0);
      sB1g0 = MFMA(aB1, bd_l[0][kk], sB1g0);
      sB1g1 = MFMA(aB1, bd_h[1][kk], sB1g1);
      sB1g1 = MFMA(aB1, bd_l[1][kk], sB1g1);
    }

    // ---- per-group softmax update (4 shfl per pair)
    float mx0 = fmaxf(fmaxf(fmaxf(sA0g0[0], sA0g0[1]), fmaxf(sA0g0[2], sA0g0[3])),
                      fmaxf(fmaxf(sA1g0[0], sA1g0[1]), fmaxf(sA1g0[2], sA1g0[3])));
    mx0 = fmaxf(mx0, fmaxf(fmaxf(fmaxf(sB0g0[0], sB0g0[1]), fmaxf(sB0g0[2], sB0g0[3])),
                           fmaxf(fmaxf(sB1g0[0], sB1g0[1]), fmaxf(sB1g0[2], sB1g0[3]))));
    float mx1 = fmaxf(fmaxf(fmaxf(sA0g1[0], sA0g1[1]), fmaxf(sA0g1[2], sA0g1[3])),
                      fmaxf(fmaxf(sA1g1[0], sA1g1[1]), fmaxf(sA1g1[2], sA1g1[3])));
    mx1 = fmaxf(mx1, fmaxf(fmaxf(fmaxf(sB0g1[0], sB0g1[1]), fmaxf(sB0g1[2], sB0g1[3])),
                           fmaxf(fmaxf(sB1g1[0], sB1g1[1]), fmaxf(sB1g1[2], sB1g1[3]))));
    mx0 = fmaxf(mx0, __shfl_xor(mx0, 16, 64));
    mx0 = fmaxf(mx0, __shfl_xor(mx0, 32, 64));
    mx1 = fmaxf(mx1, __shfl_xor(mx1, 16, 64));
    mx1 = fmaxf(mx1, __shfl_xor(mx1, 32, 64));
    const bool ok = (mx0 <= m0 + 4.0f) && (mx1 <= m1 + 4.0f);
    if (!__all(ok)) {                  // defer-max, per-group rescale
      const float nm0 = fmaxf(m0, mx0);
      const float sc0 = __expf(m0 - nm0);
      const float nm1 = fmaxf(m1, mx1);
      const float sc1 = __expf(m1 - nm1);
      m0 = nm0; m1 = nm1; l0 *= sc0; l1 *= sc1;
#pragma unroll
      for (int nt = 0; nt < 16; ++nt) {
#pragma unroll
        for (int r = 0; r < 4; ++r) { acc0[nt][r] *= sc0; acc1[nt][r] *= sc1; }
      }
    }

    // ---- tile A: exp + pack both groups, PV (A-frag read once, 2 MFMA)
    {
      union { unsigned u[4]; s16x8 v; } pb0, pb1;
      {
        float t0[4], t1[4];
#pragma unroll
        for (int r = 0; r < 4; ++r) {
          t0[r] = __expf(sA0g0[r] - m0);
          t1[r] = __expf(sA1g0[r] - m0);
          l0 += t0[r] + t1[r];
        }
        pb0.u[0] = pk2h(t0[0], t0[1]); pb0.u[1] = pk2h(t0[2], t0[3]);
        pb0.u[2] = pk2h(t1[0], t1[1]); pb0.u[3] = pk2h(t1[2], t1[3]);
#pragma unroll
        for (int r = 0; r < 4; ++r) {
          t0[r] = __expf(sA0g1[r] - m1);
          t1[r] = __expf(sA1g1[r] - m1);
          l1 += t0[r] + t1[r];
        }
        pb1.u[0] = pk2h(t0[0], t0[1]); pb1.u[1] = pk2h(t0[2], t0[3]);
        pb1.u[2] = pk2h(t1[0], t1[1]); pb1.u[3] = pk2h(t1[2], t1[3]);
      }
#pragma unroll
      for (int nt = 0; nt < 16; ++nt) {
        const s16x8 ea = *(const s16x8*)&etbA[nt * 64 + g * 16 + c];
        acc0[nt] = MFMA(ea, pb0.v, acc0[nt]);
        acc1[nt] = MFMA(ea, pb1.v, acc1[nt]);
      }
    }
    // ---- tile B
    {
      union { unsigned u[4]; s16x8 v; } pb0, pb1;
      {
        float t0[4], t1[4];
#pragma unroll
        for (int r = 0; r < 4; ++r) {
          t0[r] = __expf(sB0g0[r] - m0);
          t1[r] = __expf(sB1g0[r] - m0);
          l0 += t0[r] + t1[r];
        }
        pb0.u[0] = pk2h(t0[0], t0[1]); pb0.u[1] = pk2h(t0[2], t0[3]);
        pb0.u[2] = pk2h(t1[0], t1[1]); pb0.u[3] = pk2h(t1[2], t1[3]);
#pragma unroll
        for (int r = 0; r < 4; ++r) {
          t0[r] = __expf(sB0g1[r] - m1);
          t1[r] = __expf(sB1g1[r] - m1);
          l1 += t0[r] + t1[r];
        }
        pb1.u[0] = pk2h(t0[0], t0[1]); pb1.u[1] = pk2h(t0[2], t0[3]);
        pb1.u[2] = pk2h(t1[0], t1[1]); pb1.u[3] = pk2h(t1[2], t1[3]);
      }
#pragma unroll
      for (int nt = 0; nt < 16; ++nt) {
        const s16x8 ea = *(const s16x8*)&etbB[nt * 64 + g * 16 + c];
        acc0[nt] = MFMA(ea, pb0.v, acc0[nt]);
        acc1[nt] = MFMA(ea, pb1.v, acc1[nt]);
      }
    }
    __syncthreads();                  // drains prefetch; next pair resident
  }

  // ---- final l reductions (per group)
  l0 += __shfl_xor(l0, 16, 64);
  l0 += __shfl_xor(l0, 32, 64);
  l1 += __shfl_xor(l1, 16, 64);
  l1 += __shfl_xor(l1, 32, 64);

  // ---- fp16 partials (unnormalized) + (m,l) per q, both groups
  const size_t R0 = (size_t)b * TD_ + qrow0;
  const size_t R1 = (size_t)b * TD_ + qrow1;
  unsigned short* pr0 = pacc + (((size_t)ns * NROW_) + R0) * H_;
  unsigned short* pr1 = pacc + (((size_t)ns * NROW_) + R1) * H_;
#pragma unroll
  for (int nt = 0; nt < 16; ++nt) {
    u16x4 o0, o1;
#pragma unroll
    for (int j = 0; j < 4; ++j) { o0[j] = f2h(acc0[nt][j]); o1[j] = f2h(acc1[nt][j]); }
    *(u16x4*)(pr0 + nt * 16 + g * 4) = o0;
    *(u16x4*)(pr1 + nt * 16 + g * 4) = o1;
  }
  if (g == 0) {
    pm[ns * NROW_ + R0] = m0;
    pl[ns * NROW_ + R0] = l0;
    pm[ns * NROW_ + R1] = m1;
    pl[ns * NROW_ + R1] = l1;
  }
}

// ---------------- dense2: combine NS partials -> X=[value,d] fp16 -> MFMA -> tanh
//                  (verbatim)
__global__ __launch_bounds__(256) void dense2(const unsigned short* __restrict__ pacc,
                                              const float* __restrict__ pm,
                                              const float* __restrict__ pl,
                                              const float* __restrict__ dmat,
                                              const unsigned short* __restrict__ WT,
                                              const float* __restrict__ bias,
                                              float* __restrict__ out) {
  const int row0 = blockIdx.x * 32;    // 256 blocks
  const int tid = threadIdx.x;
  const int w = tid >> 6;
  const int lane = tid & 63;
  const int ln = lane & 31, hi = lane >> 5;
  __shared__ unsigned short Xl[32][520];

  {
    const int row = tid >> 3;
    const int c0 = (tid & 7) * 32;
    const int R = row0 + row;
    float wts[NS_];
    float M = -__builtin_inff();
#pragma unroll
    for (int s = 0; s < NS_; ++s) M = fmaxf(M, pm[s * NROW_ + R]);
    float L = 0.f;
#pragma unroll
    for (int s = 0; s < NS_; ++s) {
      wts[s] = __expf(pm[s * NROW_ + R] - M);
      L += wts[s] * pl[s * NROW_ + R];
    }
    const float inv = 1.0f / L;
#pragma unroll
    for (int c8 = 0; c8 < 4; ++c8) {
      const int cc = c0 + c8 * 8;
      float o8[8];
#pragma unroll
      for (int j = 0; j < 8; ++j) o8[j] = 0.f;
#pragma unroll
      for (int s = 0; s < NS_; ++s) {
        const s16x8 v = *(const s16x8*)&pacc[(((size_t)s * NROW_) + R) * H_ + cc];
#pragma unroll
        for (int j = 0; j < 8; ++j)
          o8[j] += wts[s] * h2f((unsigned short)v[j]);
      }
      u16x4 y0, y1;
#pragma unroll
      for (int j = 0; j < 4; ++j) {
        y0[j] = f2h(o8[j] * inv);
        y1[j] = f2h(o8[4 + j] * inv);
      }
      *(u16x4*)&Xl[row][cc] = y0;
      *(u16x4*)&Xl[row][cc + 4] = y1;
    }
    const float* drow = dmat + (size_t)R * H_ + c0;
#pragma unroll
    for (int c8 = 0; c8 < 8; ++c8) {
      const fx4 v = *(const fx4*)&drow[c8 * 4];
      u16x4 y;
#pragma unroll
      for (int j = 0; j < 4; ++j) y[j] = f2h(v[j]);
      *(u16x4*)&Xl[row][256 + c0 + c8 * 4] = y;
    }
  }
  __syncthreads();

  fx16 a0, a1;
#pragma unroll
  for (int r = 0; r < 16; ++r) { a0[r] = 0.f; a1[r] = 0.f; }
  const int n0 = w * 64;
#pragma unroll
  for (int ks = 0; ks < 32; ++ks) {
    const s16x8 av = *(const s16x8*)&Xl[ln][ks * 16 + hi * 8];
    const s16x8 b0 = *(const s16x8*)(WT + (size_t)(n0 + ln) * 512 + ks * 16 + hi * 8);
    const s16x8 b1 = *(const s16x8*)(WT + (size_t)(n0 + 32 + ln) * 512 + ks * 16 + hi * 8);
    a0 = MFMA32(av, b0, a0);
    a1 = MFMA32(av, b1, a1);
  }
  const float bn0 = bias[n0 + ln];
  const float bn1 = bias[n0 + 32 + ln];
#pragma unroll
  for (int r = 0; r < 16; ++r) {
    const int rloc = (r & 3) + 8 * (r >> 2) + 4 * hi;
    const size_t ro = (size_t)(row0 + rloc) * 256;
    out[ro + n0 + ln] = tanhf(a0[r] + bn0);
    out[ro + n0 + 32 + ln] = tanhf(a1[r] + bn1);
  }
}

extern "C" void kernel_launch(void* const* d_in, const int* in_sizes, int n_in,
                              void* d_out, int out_size, void* d_ws, size_t ws_size,
                              hipStream_t stream) {
  const float* e = (const float*)d_in[0];    // [8,4096,256]
  const float* d = (const float*)d_in[1];    // [8,1024,256]
  const float* W = (const float*)d_in[2];    // [512,256]
  const float* bias = (const float*)d_in[3]; // [256]
  float* out = (float*)d_out;

  char* p = (char*)d_ws;
  const size_t EB = (size_t)B_ * TE_ * H_ * 2;       // 16 MiB
  const size_t WB = (size_t)512 * 256 * 2;           // 256 KiB
  const size_t PB = (size_t)NS_ * NROW_ * H_ * 2;    // 16 MiB (fp16 partials)
  unsigned short* eh  = (unsigned short*)p;            p += EB;
  unsigned short* eT  = (unsigned short*)p;            p += EB;
  unsigned short* WT  = (unsigned short*)p;            p += WB;
  unsigned short* pacc = (unsigned short*)p;           p += PB;
  float* pmv = (float*)p;                              p += (size_t)NS_ * NROW_ * 4;
  float* plv = (float*)p;                              // total ~48.6 MiB

  prep<<<dim3(2176), dim3(256), 0, stream>>>(e, W, eh, eT, WT);
  flash18<<<dim3(256), dim3(256), 0, stream>>>(eh, eT, d, pacc, pmv, plv);
  dense2<<<dim3(256), dim3(256), 0, stream>>>(pacc, pmv, plv, d, WT, bias, out);
}

// Round 19
// 112.651 us; speedup vs baseline: 1.0013x; 1.0013x over previous
//
#include <hip/hip_runtime.h>

// Attention_Layer: scores=d@e^T -> softmax -> value=attn@e -> tanh([value,d]@W+b)
// B=8 TE=4096 TD=1024 H=256 NH=256, f32 in/out.
// Round 19: flash15 body VERBATIM (92 VGPR, 64KB LDS, zero-shuffle PV,
// sigma-swizzle) with NS 4->8 and 512 blocks: q/block stays 128 (no staging
// duplication), chunk halves, and each CU hosts TWO independent blocks =
// 16 waves/CU (4/SIMD) -> doubled latency hiding for the latency-bound body.
// dense2 combines 8 partials. prep verbatim.

#define B_ 8
#define TE_ 4096
#define TD_ 1024
#define H_ 256
#define NS_ 8
#define CHUNK_ (TE_ / NS_)   // 512
#define NIT_ (CHUNK_ / 32)   // 16
#define NROW_ (B_ * TD_)     // 8192

typedef __attribute__((ext_vector_type(8))) short s16x8;
typedef __attribute__((ext_vector_type(8))) _Float16 h16x8;
typedef __attribute__((ext_vector_type(4))) float fx4;
typedef __attribute__((ext_vector_type(16))) float fx16;
typedef __attribute__((ext_vector_type(4))) unsigned short u16x4;

__device__ __forceinline__ h16x8 as_h(s16x8 v) {
  union { s16x8 s; h16x8 h; } u; u.s = v; return u.h;
}
#define MFMA(a, b, c) __builtin_amdgcn_mfma_f32_16x16x32_f16(as_h(a), as_h(b), c, 0, 0, 0)
#define MFMA32(a, b, c) __builtin_amdgcn_mfma_f32_32x32x16_f16(as_h(a), as_h(b), c, 0, 0, 0)

__device__ __forceinline__ unsigned short f2h(float x) {
  const _Float16 h = (_Float16)x;    // RNE
  union { _Float16 h; unsigned short s; } u; u.h = h; return u.s;
}
__device__ __forceinline__ float h2f(unsigned short s) {
  union { unsigned short s; _Float16 h; } u; u.s = s; return (float)u.h;
}
// pack two f32 into one u32 of 2 fp16 (lo = f0, hi = f1)
__device__ __forceinline__ unsigned pk2h(float f0, float f1) {
  return (unsigned)f2h(f0) | ((unsigned)f2h(f1) << 16);
}
__device__ __forceinline__ void gload_lds16(const void* g, void* l) {
  __builtin_amdgcn_global_load_lds(
      (const __attribute__((address_space(1))) void*)g,
      (__attribute__((address_space(3))) void*)l, 16, 0, 0);
}

// ---------------- prep: e -> eh fp16 [b][TE][H], eT fp16 [b][H][TE];
//                  W -> WT fp16 [256n][512k]   (verbatim)
__global__ __launch_bounds__(256) void prep(const float* __restrict__ e,
                                            const float* __restrict__ W,
                                            unsigned short* __restrict__ eh,
                                            unsigned short* __restrict__ eT,
                                            unsigned short* __restrict__ WT) {
  __shared__ unsigned short lt[64][65];
  __shared__ float wl[32][33];
  const int bid = blockIdx.x;
  const int tid = threadIdx.x;
  if (bid < 2048) {                   // e part: 8 * 64 * 4 tiles
    const int b = bid >> 8;
    const int s0 = ((bid >> 2) & 63) * 64;
    const int h0 = (bid & 3) * 64;
#pragma unroll
    for (int i = 0; i < 4; ++i) {
      const int row = (tid >> 4) + 16 * i;
      const int col = (tid & 15) * 4;
      const size_t go = (((size_t)b * TE_) + s0 + row) * H_ + h0 + col;
      const fx4 v = *(const fx4*)&e[go];
      u16x4 hv;
#pragma unroll
      for (int j = 0; j < 4; ++j) {
        const unsigned short hb = f2h(v[j]);
        hv[j] = hb;
        lt[row][col + j] = hb;
      }
      *(u16x4*)&eh[go] = hv;
    }
    __syncthreads();
#pragma unroll
    for (int i = 0; i < 2; ++i) {
      const int idx = tid + 256 * i;
      const int hh = idx >> 3;
      const int sc = (idx & 7) * 8;
      s16x8 v;
#pragma unroll
      for (int j = 0; j < 8; ++j) v[j] = (short)lt[sc + j][hh];
      *(s16x8*)&eT[(((size_t)b * H_) + h0 + hh) * TE_ + s0 + sc] = v;
    }
  } else {                            // W part: 128 tiles of 32x32
    const int tb = bid - 2048;
    const int k0 = (tb >> 3) * 32, n0 = (tb & 7) * 32;
    const int r = tid >> 3, c4 = (tid & 7) * 4;
    const fx4 v = *(const fx4*)&W[(size_t)(k0 + r) * 256 + n0 + c4];
#pragma unroll
    for (int j = 0; j < 4; ++j) wl[r][c4 + j] = v[j];
    __syncthreads();
    u16x4 o;
#pragma unroll
    for (int j = 0; j < 4; ++j) o[j] = f2h(wl[c4 + j][r]);
    *(u16x4*)&WT[(size_t)(n0 + r) * 512 + k0 + c4] = o;
  }
}

// ---------------- flash19: 512 blocks = b(8)|qb(8)|ns(8); 8 waves x 16 q
//                  (flash15 body verbatim; 64KB LDS -> 2 blocks/CU)
__global__ __launch_bounds__(512, 2) void flash19(
    const unsigned short* __restrict__ eh_g, const unsigned short* __restrict__ eT_g,
    const float* __restrict__ dmat,
    unsigned short* __restrict__ pacc, float* __restrict__ pm,
    float* __restrict__ pl) {
  const int bid = blockIdx.x;
  const int ns = bid & 7;             // 8-way KV split, flash5-proven mapping
  const int qb = (bid >> 3) & 7;
  const int b = bid >> 6;
  const int tid = threadIdx.x;
  const int w = tid >> 6;
  const int lane = tid & 63;
  const int g = lane >> 4, c = lane & 15;
  const int qrow = qb * 128 + w * 16 + c;

  __shared__ uint4 smem[2][2][1024];  // 64 KB: dbuf x {eh, eT} -> 2 blocks/CU

  // ---- staging sources; e store-swizzle key sigma(s) = (s&3)|(((s>>3)&1)<<2)
  const unsigned short *peh0, *peh1, *pet0, *pet1;
  {
    const size_t ebase = ((size_t)b * TE_ + ns * CHUNK_) * H_;
    const size_t tbase = (size_t)b * H_ * TE_ + ns * CHUNK_;
    int L = tid;
    int s = L >> 5, ch = L & 31;
    int sg = (s & 3) | (((s >> 3) & 1) << 2);
    peh0 = eh_g + ebase + s * H_ + (ch ^ sg) * 8;
    int h2 = (L >> 6) * 16 + (L & 15), sc = ((L >> 4) & 3) * 8;
    pet0 = eT_g + tbase + (size_t)h2 * TE_ + sc;
    L = tid + 512;
    s = L >> 5; ch = L & 31;
    sg = (s & 3) | (((s >> 3) & 1) << 2);
    peh1 = eh_g + ebase + s * H_ + (ch ^ sg) * 8;
    h2 = (L >> 6) * 16 + (L & 15); sc = ((L >> 4) & 3) * 8;
    pet1 = eT_g + tbase + (size_t)h2 * TE_ + sc;
  }
  auto STAGE = [&](int buf) {
    uint4* ehb = smem[buf][0];
    uint4* etb = smem[buf][1];
    gload_lds16(peh0, &ehb[tid]);
    gload_lds16(peh1, &ehb[tid + 512]);
    gload_lds16(pet0, &etb[tid]);
    gload_lds16(pet1, &etb[tid + 512]);
    peh0 += 32 * H_; peh1 += 32 * H_;
    pet0 += 32; pet1 += 32;
  };

  STAGE(0);                           // tile 0 in flight during d-preload

  // ---- d B-frags hi/lo fp16 in registers (d exact: dh + dl)
  s16x8 bd_h[8], bd_l[8];
  {
    const float* dr = dmat + ((size_t)b * TD_ + qrow) * H_;
#pragma unroll
    for (int kk = 0; kk < 8; ++kk) {
      const fx4 x0 = *(const fx4*)&dr[kk * 32 + g * 8];
      const fx4 x1 = *(const fx4*)&dr[kk * 32 + g * 8 + 4];
      s16x8 hh, ll;
#pragma unroll
      for (int j = 0; j < 4; ++j) {
        unsigned short hb = f2h(x0[j]);
        hh[j] = (short)hb; ll[j] = (short)f2h(x0[j] - h2f(hb));
        hb = f2h(x1[j]);
        hh[4 + j] = (short)hb; ll[4 + j] = (short)f2h(x1[j] - h2f(hb));
      }
      bd_h[kk] = hh; bd_l[kk] = ll;
    }
  }

  fx4 acc[16];
#pragma unroll
  for (int nt = 0; nt < 16; ++nt) acc[nt] = (fx4){0.f, 0.f, 0.f, 0.f};
  float m = -__builtin_inff(), l = 0.f;
  const int xr = (c & 3) | (((c >> 2) & 1) << 2);   // = sigma(rho) = sigma(rho+4)
  const int rho = (c & 3) + (c >> 2) * 8;           // s-row permutation

  __syncthreads();                    // tile 0 resident

  for (int it = 0; it < NIT_; ++it) {
    const int cur = it & 1;
    if (it + 1 < NIT_) STAGE(cur ^ 1);   // prefetch next tile (drained at barrier)

    const uint4* ehb = smem[cur][0];
    const uint4* etb = smem[cur][1];

    // ---- QK^T (swapped, s-permuted A): lane (g,c) output = P[s=g*8+..][q=c]
    fx4 sa0 = (fx4){0.f, 0.f, 0.f, 0.f};   // -> s = g*8 + r
    fx4 sa1 = (fx4){0.f, 0.f, 0.f, 0.f};   // -> s = g*8 + 4 + r
#pragma unroll
    for (int kk = 0; kk < 8; ++kk) {
      const int sl = (kk * 4 + g) ^ xr;
      const s16x8 ah0 = *(const s16x8*)&ehb[rho * 32 + sl];
      const s16x8 ah1 = *(const s16x8*)&ehb[(rho + 4) * 32 + sl];
      sa0 = MFMA(ah0, bd_h[kk], sa0);
      sa0 = MFMA(ah0, bd_l[kk], sa0);
      sa1 = MFMA(ah1, bd_h[kk], sa1);
      sa1 = MFMA(ah1, bd_l[kk], sa1);
    }

    // ---- online softmax (q=c lives on 4 g-lanes: 2 shfl rounds)
    float mx = fmaxf(fmaxf(fmaxf(sa0[0], sa0[1]), fmaxf(sa0[2], sa0[3])),
                     fmaxf(fmaxf(sa1[0], sa1[1]), fmaxf(sa1[2], sa1[3])));
    mx = fmaxf(mx, __shfl_xor(mx, 16, 64));
    mx = fmaxf(mx, __shfl_xor(mx, 32, 64));
    if (!__all(mx <= m + 4.0f)) {      // defer-max
      const float nm = fmaxf(m, mx);
      const float sc = __expf(m - nm);
      m = nm; l *= sc;
#pragma unroll
      for (int nt = 0; nt < 16; ++nt) {
#pragma unroll
        for (int r = 0; r < 4; ++r) acc[nt][r] *= sc;
      }
    }
    float t0[4], t1[4];
    float rs = 0.f;
#pragma unroll
    for (int r = 0; r < 4; ++r) {
      t0[r] = __expf(sa0[r] - m);      // fp16-rounded inside pk2h below
      t1[r] = __expf(sa1[r] - m);
      rs += t0[r] + t1[r];             // raw-f32 l: systematic err ~8e-6
    }
    rs += __shfl_xor(rs, 16, 64);
    rs += __shfl_xor(rs, 32, 64);
    l += rs;

    // ---- PV B-frag is LANE-LOCAL: k=g*8+j -> {t0[0..3], t1[0..3]}
    union { unsigned u[4]; s16x8 v; } pb;
    pb.u[0] = pk2h(t0[0], t0[1]);
    pb.u[1] = pk2h(t0[2], t0[3]);
    pb.u[2] = pk2h(t1[0], t1[1]);
    pb.u[3] = pk2h(t1[2], t1[3]);

    // ---- PV: value^T[h][q] += eT(A, [nt][g][c] layout) x P^T(B)
#pragma unroll
    for (int nt = 0; nt < 16; ++nt) {
      const s16x8 ea = *(const s16x8*)&etb[nt * 64 + g * 16 + c];
      acc[nt] = MFMA(ea, pb.v, acc[nt]);
    }
    __syncthreads();                  // drains prefetch; next tile resident
  }

  // ---- fp16 partials (unnormalized) + (m,l) per q
  const size_t R = (size_t)b * TD_ + qrow;
  unsigned short* pr = pacc + (((size_t)ns * NROW_) + R) * H_;
#pragma unroll
  for (int nt = 0; nt < 16; ++nt) {
    u16x4 o;
#pragma unroll
    for (int j = 0; j < 4; ++j) o[j] = f2h(acc[nt][j]);
    *(u16x4*)(pr + nt * 16 + g * 4) = o;
  }
  if (g == 0) {
    pm[ns * NROW_ + R] = m;
    pl[ns * NROW_ + R] = l;
  }
}

// ---------------- dense2: combine NS partials -> X=[value,d] fp16 -> MFMA -> tanh
//                  (verbatim; NS_ = 8)
__global__ __launch_bounds__(256) void dense2(const unsigned short* __restrict__ pacc,
                                              const float* __restrict__ pm,
                                              const float* __restrict__ pl,
                                              const float* __restrict__ dmat,
                                              const unsigned short* __restrict__ WT,
                                              const float* __restrict__ bias,
                                              float* __restrict__ out) {
  const int row0 = blockIdx.x * 32;    // 256 blocks
  const int tid = threadIdx.x;
  const int w = tid >> 6;
  const int lane = tid & 63;
  const int ln = lane & 31, hi = lane >> 5;
  __shared__ unsigned short Xl[32][520];

  {
    const int row = tid >> 3;
    const int c0 = (tid & 7) * 32;
    const int R = row0 + row;
    float wts[NS_];
    float M = -__builtin_inff();
#pragma unroll
    for (int s = 0; s < NS_; ++s) M = fmaxf(M, pm[s * NROW_ + R]);
    float L = 0.f;
#pragma unroll
    for (int s = 0; s < NS_; ++s) {
      wts[s] = __expf(pm[s * NROW_ + R] - M);
      L += wts[s] * pl[s * NROW_ + R];
    }
    const float inv = 1.0f / L;
#pragma unroll
    for (int c8 = 0; c8 < 4; ++c8) {
      const int cc = c0 + c8 * 8;
      float o8[8];
#pragma unroll
      for (int j = 0; j < 8; ++j) o8[j] = 0.f;
#pragma unroll
      for (int s = 0; s < NS_; ++s) {
        const s16x8 v = *(const s16x8*)&pacc[(((size_t)s * NROW_) + R) * H_ + cc];
#pragma unroll
        for (int j = 0; j < 8; ++j)
          o8[j] += wts[s] * h2f((unsigned short)v[j]);
      }
      u16x4 y0, y1;
#pragma unroll
      for (int j = 0; j < 4; ++j) {
        y0[j] = f2h(o8[j] * inv);
        y1[j] = f2h(o8[4 + j] * inv);
      }
      *(u16x4*)&Xl[row][cc] = y0;
      *(u16x4*)&Xl[row][cc + 4] = y1;
    }
    const float* drow = dmat + (size_t)R * H_ + c0;
#pragma unroll
    for (int c8 = 0; c8 < 8; ++c8) {
      const fx4 v = *(const fx4*)&drow[c8 * 4];
      u16x4 y;
#pragma unroll
      for (int j = 0; j < 4; ++j) y[j] = f2h(v[j]);
      *(u16x4*)&Xl[row][256 + c0 + c8 * 4] = y;
    }
  }
  __syncthreads();

  fx16 a0, a1;
#pragma unroll
  for (int r = 0; r < 16; ++r) { a0[r] = 0.f; a1[r] = 0.f; }
  const int n0 = w * 64;
#pragma unroll
  for (int ks = 0; ks < 32; ++ks) {
    const s16x8 av = *(const s16x8*)&Xl[ln][ks * 16 + hi * 8];
    const s16x8 b0 = *(const s16x8*)(WT + (size_t)(n0 + ln) * 512 + ks * 16 + hi * 8);
    const s16x8 b1 = *(const s16x8*)(WT + (size_t)(n0 + 32 + ln) * 512 + ks * 16 + hi * 8);
    a0 = MFMA32(av, b0, a0);
    a1 = MFMA32(av, b1, a1);
  }
  const float bn0 = bias[n0 + ln];
  const float bn1 = bias[n0 + 32 + ln];
#pragma unroll
  for (int r = 0; r < 16; ++r) {
    const int rloc = (r & 3) + 8 * (r >> 2) + 4 * hi;
    const size_t ro = (size_t)(row0 + rloc) * 256;
    out[ro + n0 + ln] = tanhf(a0[r] + bn0);
    out[ro + n0 + 32 + ln] = tanhf(a1[r] + bn1);
  }
}

extern "C" void kernel_launch(void* const* d_in, const int* in_sizes, int n_in,
                              void* d_out, int out_size, void* d_ws, size_t ws_size,
                              hipStream_t stream) {
  const float* e = (const float*)d_in[0];    // [8,4096,256]
  const float* d = (const float*)d_in[1];    // [8,1024,256]
  const float* W = (const float*)d_in[2];    // [512,256]
  const float* bias = (const float*)d_in[3]; // [256]
  float* out = (float*)d_out;

  char* p = (char*)d_ws;
  const size_t EB = (size_t)B_ * TE_ * H_ * 2;       // 16 MiB
  const size_t WB = (size_t)512 * 256 * 2;           // 256 KiB
  const size_t PB = (size_t)NS_ * NROW_ * H_ * 2;    // 32 MiB (fp16 partials)
  unsigned short* eh  = (unsigned short*)p;            p += EB;
  unsigned short* eT  = (unsigned short*)p;            p += EB;
  unsigned short* WT  = (unsigned short*)p;            p += WB;
  unsigned short* pacc = (unsigned short*)p;           p += PB;
  float* pmv = (float*)p;                              p += (size_t)NS_ * NROW_ * 4;
  float* plv = (float*)p;                              // total ~65 MiB

  prep<<<dim3(2176), dim3(256), 0, stream>>>(e, W, eh, eT, WT);
  flash19<<<dim3(512), dim3(512), 0, stream>>>(eh, eT, d, pacc, pmv, plv);
  dense2<<<dim3(256), dim3(256), 0, stream>>>(pacc, pmv, plv, d, WT, bias, out);
}

// Round 21
// 91.924 us; speedup vs baseline: 1.2271x; 1.2255x over previous
//
#include <hip/hip_runtime.h>

// Attention_Layer: scores=d@e^T -> softmax -> value=attn@e -> tanh([value,d]@W+b)
// B=8 TE=4096 TD=1024 H=256 NH=256, f32 in/out.
// Round 21: round-20 (champion + VALU micro-opts) with the cvt_pkrtz type fix:
// the builtin returns __fp16x2, not _Float16x2 -- union uses the builtin's type.
// - P packing via v_cvt_pkrtz_f16_f32 (1 op, was ~4) incl. pacc epilogue
// - max-reduction regrouped for v_max3_f32 fusion
// Structure/staging/swizzles/softmax/PV/prep/dense2 verbatim from round 16.

#define B_ 8
#define TE_ 4096
#define TD_ 1024
#define H_ 256
#define NS_ 4
#define CHUNK_ (TE_ / NS_)   // 1024
#define NIT_ (CHUNK_ / 32)   // 32 tiles -> 16 pairs
#define NROW_ (B_ * TD_)     // 8192

typedef __attribute__((ext_vector_type(8))) short s16x8;
typedef __attribute__((ext_vector_type(8))) _Float16 h16x8;
typedef __attribute__((ext_vector_type(2))) __fp16 fp16x2;
typedef __attribute__((ext_vector_type(4))) float fx4;
typedef __attribute__((ext_vector_type(16))) float fx16;
typedef __attribute__((ext_vector_type(4))) unsigned short u16x4;

__device__ __forceinline__ h16x8 as_h(s16x8 v) {
  union { s16x8 s; h16x8 h; } u; u.s = v; return u.h;
}
#define MFMA(a, b, c) __builtin_amdgcn_mfma_f32_16x16x32_f16(as_h(a), as_h(b), c, 0, 0, 0)
#define MFMA32(a, b, c) __builtin_amdgcn_mfma_f32_32x32x16_f16(as_h(a), as_h(b), c, 0, 0, 0)

__device__ __forceinline__ unsigned short f2h(float x) {
  const _Float16 h = (_Float16)x;    // RNE
  union { _Float16 h; unsigned short s; } u; u.h = h; return u.s;
}
__device__ __forceinline__ float h2f(unsigned short s) {
  union { unsigned short s; _Float16 h; } u; u.s = s; return (float)u.h;
}
// pack two f32 into one u32 of 2 fp16 in ONE instr (v_cvt_pkrtz_f16_f32)
__device__ __forceinline__ unsigned pk2h(float f0, float f1) {
  union { fp16x2 h; unsigned u; } u;
  u.h = __builtin_amdgcn_cvt_pkrtz(f0, f1);
  return u.u;
}
__device__ __forceinline__ float max3f(float a, float b, float c) {
  return fmaxf(fmaxf(a, b), c);      // fuses to v_max3_f32
}
__device__ __forceinline__ void gload_lds16(const void* g, void* l) {
  __builtin_amdgcn_global_load_lds(
      (const __attribute__((address_space(1))) void*)g,
      (__attribute__((address_space(3))) void*)l, 16, 0, 0);
}

// ---------------- prep: e -> eh fp16 [b][TE][H], eT fp16 [b][H][TE];
//                  W -> WT fp16 [256n][512k]   (round-16 verbatim)
__global__ __launch_bounds__(256) void prep(const float* __restrict__ e,
                                            const float* __restrict__ W,
                                            unsigned short* __restrict__ eh,
                                            unsigned short* __restrict__ eT,
                                            unsigned short* __restrict__ WT) {
  __shared__ unsigned short lt[64][65];
  __shared__ float wl[32][33];
  const int bid = blockIdx.x;
  const int tid = threadIdx.x;
  if (bid < 2048) {                   // e part: 8 * 64 * 4 tiles
    const int b = bid >> 8;
    const int s0 = ((bid >> 2) & 63) * 64;
    const int h0 = (bid & 3) * 64;
#pragma unroll
    for (int i = 0; i < 4; ++i) {
      const int row = (tid >> 4) + 16 * i;
      const int col = (tid & 15) * 4;
      const size_t go = (((size_t)b * TE_) + s0 + row) * H_ + h0 + col;
      const fx4 v = *(const fx4*)&e[go];
      u16x4 hv;
#pragma unroll
      for (int j = 0; j < 4; ++j) {
        const unsigned short hb = f2h(v[j]);
        hv[j] = hb;
        lt[row][col + j] = hb;
      }
      *(u16x4*)&eh[go] = hv;
    }
    __syncthreads();
#pragma unroll
    for (int i = 0; i < 2; ++i) {
      const int idx = tid + 256 * i;
      const int hh = idx >> 3;
      const int sc = (idx & 7) * 8;
      s16x8 v;
#pragma unroll
      for (int j = 0; j < 8; ++j) v[j] = (short)lt[sc + j][hh];
      *(s16x8*)&eT[(((size_t)b * H_) + h0 + hh) * TE_ + s0 + sc] = v;
    }
  } else {                            // W part: 128 tiles of 32x32
    const int tb = bid - 2048;
    const int k0 = (tb >> 3) * 32, n0 = (tb & 7) * 32;
    const int r = tid >> 3, c4 = (tid & 7) * 4;
    const fx4 v = *(const fx4*)&W[(size_t)(k0 + r) * 256 + n0 + c4];
#pragma unroll
    for (int j = 0; j < 4; ++j) wl[r][c4 + j] = v[j];
    __syncthreads();
    u16x4 o;
#pragma unroll
    for (int j = 0; j < 4; ++j) o[j] = f2h(wl[c4 + j][r]);
    *(u16x4*)&WT[(size_t)(n0 + r) * 512 + k0 + c4] = o;
  }
}

// ---------------- flash21: 256 blocks = b(8)|qb(8)|ns(4); 8 waves x 16 q
__global__ __launch_bounds__(512, 2) void flash21(
    const unsigned short* __restrict__ eh_g, const unsigned short* __restrict__ eT_g,
    const float* __restrict__ dmat,
    unsigned short* __restrict__ pacc, float* __restrict__ pm,
    float* __restrict__ pl) {
  const int bid = blockIdx.x;
  const int ns = bid & 3;             // 4-way KV split (proven mapping)
  const int qb = (bid >> 2) & 7;
  const int b = bid >> 5;
  const int tid = threadIdx.x;
  const int w = tid >> 6;
  const int lane = tid & 63;
  const int g = lane >> 4, c = lane & 15;
  const int qrow = qb * 128 + w * 16 + c;

  __shared__ uint4 smem[4][2][1024];  // 128 KB: 4-deep x {eh, eT}

  // ---- staging sources; e store-swizzle key sigma(s) = (s&3)|(((s>>3)&1)<<2)
  const unsigned short *peh0, *peh1, *pet0, *pet1;
  {
    const size_t ebase = ((size_t)b * TE_ + ns * CHUNK_) * H_;
    const size_t tbase = (size_t)b * H_ * TE_ + ns * CHUNK_;
    int L = tid;
    int s = L >> 5, ch = L & 31;
    int sg = (s & 3) | (((s >> 3) & 1) << 2);
    peh0 = eh_g + ebase + s * H_ + (ch ^ sg) * 8;
    int h2 = (L >> 6) * 16 + (L & 15), sc = ((L >> 4) & 3) * 8;
    pet0 = eT_g + tbase + (size_t)h2 * TE_ + sc;
    L = tid + 512;
    s = L >> 5; ch = L & 31;
    sg = (s & 3) | (((s >> 3) & 1) << 2);
    peh1 = eh_g + ebase + s * H_ + (ch ^ sg) * 8;
    h2 = (L >> 6) * 16 + (L & 15); sc = ((L >> 4) & 3) * 8;
    pet1 = eT_g + tbase + (size_t)h2 * TE_ + sc;
  }
  auto STAGE = [&](int buf) {
    uint4* ehb = smem[buf][0];
    uint4* etb = smem[buf][1];
    gload_lds16(peh0, &ehb[tid]);
    gload_lds16(peh1, &ehb[tid + 512]);
    gload_lds16(pet0, &etb[tid]);
    gload_lds16(pet1, &etb[tid + 512]);
    peh0 += 32 * H_; peh1 += 32 * H_;
    pet0 += 32; pet1 += 32;
  };

  STAGE(0);                           // tiles 0,1 in flight during d-preload
  STAGE(1);

  // ---- d B-frags hi/lo fp16 in registers (d exact: dh + dl)
  s16x8 bd_h[8], bd_l[8];
  {
    const float* dr = dmat + ((size_t)b * TD_ + qrow) * H_;
#pragma unroll
    for (int kk = 0; kk < 8; ++kk) {
      const fx4 x0 = *(const fx4*)&dr[kk * 32 + g * 8];
      const fx4 x1 = *(const fx4*)&dr[kk * 32 + g * 8 + 4];
      s16x8 hh, ll;
#pragma unroll
      for (int j = 0; j < 4; ++j) {
        unsigned short hb = f2h(x0[j]);
        hh[j] = (short)hb; ll[j] = (short)f2h(x0[j] - h2f(hb));
        hb = f2h(x1[j]);
        hh[4 + j] = (short)hb; ll[4 + j] = (short)f2h(x1[j] - h2f(hb));
      }
      bd_h[kk] = hh; bd_l[kk] = ll;
    }
  }

  fx4 acc[16];
#pragma unroll
  for (int nt = 0; nt < 16; ++nt) acc[nt] = (fx4){0.f, 0.f, 0.f, 0.f};
  float m = -__builtin_inff(), l_lane = 0.f;
  const int xr = (c & 3) | (((c >> 2) & 1) << 2);   // = sigma(rho) = sigma(rho+4)
  const int rho = (c & 3) + (c >> 2) * 8;           // s-row permutation

  __syncthreads();                    // tiles 0,1 resident

  for (int p = 0; p < NIT_ / 2; ++p) {
    const int bufA = (p & 1) << 1;    // 0,2,0,2,...
    const int bufB = bufA + 1;        // 1,3,1,3,...
    if (p + 1 < NIT_ / 2) {           // prefetch next pair (drained at barrier)
      STAGE(bufA ^ 2);
      STAGE(bufB ^ 2);
    }
    const uint4* ehbA = smem[bufA][0];
    const uint4* etbA = smem[bufA][1];
    const uint4* ehbB = smem[bufB][0];
    const uint4* etbB = smem[bufB][1];

    // ---- QK^T for both tiles (4 independent chains): P[s=g*8+..][q=c]
    fx4 sA0 = (fx4){0.f, 0.f, 0.f, 0.f};   // tile A, s = g*8 + r
    fx4 sA1 = (fx4){0.f, 0.f, 0.f, 0.f};   // tile A, s = g*8 + 4 + r
    fx4 sB0 = (fx4){0.f, 0.f, 0.f, 0.f};   // tile B
    fx4 sB1 = (fx4){0.f, 0.f, 0.f, 0.f};
#pragma unroll
    for (int kk = 0; kk < 8; ++kk) {
      const int sl = (kk * 4 + g) ^ xr;
      const s16x8 aA0 = *(const s16x8*)&ehbA[rho * 32 + sl];
      const s16x8 aA1 = *(const s16x8*)&ehbA[(rho + 4) * 32 + sl];
      const s16x8 aB0 = *(const s16x8*)&ehbB[rho * 32 + sl];
      const s16x8 aB1 = *(const s16x8*)&ehbB[(rho + 4) * 32 + sl];
      sA0 = MFMA(aA0, bd_h[kk], sA0);
      sA0 = MFMA(aA0, bd_l[kk], sA0);
      sA1 = MFMA(aA1, bd_h[kk], sA1);
      sA1 = MFMA(aA1, bd_l[kk], sA1);
      sB0 = MFMA(aB0, bd_h[kk], sB0);
      sB0 = MFMA(aB0, bd_l[kk], sB0);
      sB1 = MFMA(aB1, bd_h[kk], sB1);
      sB1 = MFMA(aB1, bd_l[kk], sB1);
    }

    // ---- ONE softmax update per 64 s (2 shfl; l deferred); v_max3 tree
    float mx;
    {
      const float a0 = max3f(sA0[0], sA0[1], sA0[2]);
      const float a1 = max3f(sA0[3], sA1[0], sA1[1]);
      const float a2 = max3f(sA1[2], sA1[3], sB0[0]);
      const float a3 = max3f(sB0[1], sB0[2], sB0[3]);
      const float a4 = max3f(sB1[0], sB1[1], sB1[2]);
      const float b0 = max3f(a0, a1, a2);
      const float b1 = max3f(a3, a4, sB1[3]);
      mx = fmaxf(b0, b1);
    }
    mx = fmaxf(mx, __shfl_xor(mx, 16, 64));
    mx = fmaxf(mx, __shfl_xor(mx, 32, 64));
    if (!__all(mx <= m + 4.0f)) {      // defer-max
      const float nm = fmaxf(m, mx);
      const float sc = __expf(m - nm);
      m = nm; l_lane *= sc;
#pragma unroll
      for (int nt = 0; nt < 16; ++nt) {
#pragma unroll
        for (int r = 0; r < 4; ++r) acc[nt][r] *= sc;
      }
    }

    // ---- tile A: exp, per-lane l, pack (pkrtz), PV
    {
      float t0[4], t1[4];
#pragma unroll
      for (int r = 0; r < 4; ++r) {
        t0[r] = __expf(sA0[r] - m);
        t1[r] = __expf(sA1[r] - m);
        l_lane += t0[r] + t1[r];
      }
      union { unsigned u[4]; s16x8 v; } pb;
      pb.u[0] = pk2h(t0[0], t0[1]);
      pb.u[1] = pk2h(t0[2], t0[3]);
      pb.u[2] = pk2h(t1[0], t1[1]);
      pb.u[3] = pk2h(t1[2], t1[3]);
#pragma unroll
      for (int nt = 0; nt < 16; ++nt) {
        const s16x8 ea = *(const s16x8*)&etbA[nt * 64 + g * 16 + c];
        acc[nt] = MFMA(ea, pb.v, acc[nt]);
      }
    }
    // ---- tile B
    {
      float t0[4], t1[4];
#pragma unroll
      for (int r = 0; r < 4; ++r) {
        t0[r] = __expf(sB0[r] - m);
        t1[r] = __expf(sB1[r] - m);
        l_lane += t0[r] + t1[r];
      }
      union { unsigned u[4]; s16x8 v; } pb;
      pb.u[0] = pk2h(t0[0], t0[1]);
      pb.u[1] = pk2h(t0[2], t0[3]);
      pb.u[2] = pk2h(t1[0], t1[1]);
      pb.u[3] = pk2h(t1[2], t1[3]);
#pragma unroll
      for (int nt = 0; nt < 16; ++nt) {
        const s16x8 ea = *(const s16x8*)&etbB[nt * 64 + g * 16 + c];
        acc[nt] = MFMA(ea, pb.v, acc[nt]);
      }
    }
    __syncthreads();                  // drains prefetch; next pair resident
  }

  // ---- final l reduction across the 4 g-lanes (deferred from the loop)
  float l = l_lane;
  l += __shfl_xor(l, 16, 64);
  l += __shfl_xor(l, 32, 64);

  // ---- fp16 partials (unnormalized, pkrtz-packed) + (m,l) per q
  const size_t R = (size_t)b * TD_ + qrow;
  unsigned short* pr = pacc + (((size_t)ns * NROW_) + R) * H_;
#pragma unroll
  for (int nt = 0; nt < 16; ++nt) {
    union { unsigned u[2]; u16x4 v; } o;
    o.u[0] = pk2h(acc[nt][0], acc[nt][1]);
    o.u[1] = pk2h(acc[nt][2], acc[nt][3]);
    *(u16x4*)(pr + nt * 16 + g * 4) = o.v;
  }
  if (g == 0) {
    pm[ns * NROW_ + R] = m;
    pl[ns * NROW_ + R] = l;
  }
}

// ---------------- dense2: combine NS partials -> X=[value,d] fp16 -> MFMA -> tanh
//                  (round-16 verbatim)
__global__ __launch_bounds__(256) void dense2(const unsigned short* __restrict__ pacc,
                                              const float* __restrict__ pm,
                                              const float* __restrict__ pl,
                                              const float* __restrict__ dmat,
                                              const unsigned short* __restrict__ WT,
                                              const float* __restrict__ bias,
                                              float* __restrict__ out) {
  const int row0 = blockIdx.x * 32;    // 256 blocks
  const int tid = threadIdx.x;
  const int w = tid >> 6;
  const int lane = tid & 63;
  const int ln = lane & 31, hi = lane >> 5;
  __shared__ unsigned short Xl[32][520];

  {
    const int row = tid >> 3;
    const int c0 = (tid & 7) * 32;
    const int R = row0 + row;
    float wts[NS_];
    float M = -__builtin_inff();
#pragma unroll
    for (int s = 0; s < NS_; ++s) M = fmaxf(M, pm[s * NROW_ + R]);
    float L = 0.f;
#pragma unroll
    for (int s = 0; s < NS_; ++s) {
      wts[s] = __expf(pm[s * NROW_ + R] - M);
      L += wts[s] * pl[s * NROW_ + R];
    }
    const float inv = 1.0f / L;
#pragma unroll
    for (int c8 = 0; c8 < 4; ++c8) {
      const int cc = c0 + c8 * 8;
      float o8[8];
#pragma unroll
      for (int j = 0; j < 8; ++j) o8[j] = 0.f;
#pragma unroll
      for (int s = 0; s < NS_; ++s) {
        const s16x8 v = *(const s16x8*)&pacc[(((size_t)s * NROW_) + R) * H_ + cc];
#pragma unroll
        for (int j = 0; j < 8; ++j)
          o8[j] += wts[s] * h2f((unsigned short)v[j]);
      }
      u16x4 y0, y1;
#pragma unroll
      for (int j = 0; j < 4; ++j) {
        y0[j] = f2h(o8[j] * inv);
        y1[j] = f2h(o8[4 + j] * inv);
      }
      *(u16x4*)&Xl[row][cc] = y0;
      *(u16x4*)&Xl[row][cc + 4] = y1;
    }
    const float* drow = dmat + (size_t)R * H_ + c0;
#pragma unroll
    for (int c8 = 0; c8 < 8; ++c8) {
      const fx4 v = *(const fx4*)&drow[c8 * 4];
      u16x4 y;
#pragma unroll
      for (int j = 0; j < 4; ++j) y[j] = f2h(v[j]);
      *(u16x4*)&Xl[row][256 + c0 + c8 * 4] = y;
    }
  }
  __syncthreads();

  fx16 a0, a1;
#pragma unroll
  for (int r = 0; r < 16; ++r) { a0[r] = 0.f; a1[r] = 0.f; }
  const int n0 = w * 64;
#pragma unroll
  for (int ks = 0; ks < 32; ++ks) {
    const s16x8 av = *(const s16x8*)&Xl[ln][ks * 16 + hi * 8];
    const s16x8 b0 = *(const s16x8*)(WT + (size_t)(n0 + ln) * 512 + ks * 16 + hi * 8);
    const s16x8 b1 = *(const s16x8*)(WT + (size_t)(n0 + 32 + ln) * 512 + ks * 16 + hi * 8);
    a0 = MFMA32(av, b0, a0);
    a1 = MFMA32(av, b1, a1);
  }
  const float bn0 = bias[n0 + ln];
  const float bn1 = bias[n0 + 32 + ln];
#pragma unroll
  for (int r = 0; r < 16; ++r) {
    const int rloc = (r & 3) + 8 * (r >> 2) + 4 * hi;
    const size_t ro = (size_t)(row0 + rloc) * 256;
    out[ro + n0 + ln] = tanhf(a0[r] + bn0);
    out[ro + n0 + 32 + ln] = tanhf(a1[r] + bn1);
  }
}

extern "C" void kernel_launch(void* const* d_in, const int* in_sizes, int n_in,
                              void* d_out, int out_size, void* d_ws, size_t ws_size,
                              hipStream_t stream) {
  const float* e = (const float*)d_in[0];    // [8,4096,256]
  const float* d = (const float*)d_in[1];    // [8,1024,256]
  const float* W = (const float*)d_in[2];    // [512,256]
  const float* bias = (const float*)d_in[3]; // [256]
  float* out = (float*)d_out;

  char* p = (char*)d_ws;
  const size_t EB = (size_t)B_ * TE_ * H_ * 2;       // 16 MiB
  const size_t WB = (size_t)512 * 256 * 2;           // 256 KiB
  const size_t PB = (size_t)NS_ * NROW_ * H_ * 2;    // 16 MiB (fp16 partials)
  unsigned short* eh  = (unsigned short*)p;            p += EB;
  unsigned short* eT  = (unsigned short*)p;            p += EB;
  unsigned short* WT  = (unsigned short*)p;            p += WB;
  unsigned short* pacc = (unsigned short*)p;           p += PB;
  float* pmv = (float*)p;                              p += (size_t)NS_ * NROW_ * 4;
  float* plv = (float*)p;                              // total ~48.6 MiB

  prep<<<dim3(2176), dim3(256), 0, stream>>>(e, W, eh, eT, WT);
  flash21<<<dim3(256), dim3(512), 0, stream>>>(eh, eT, d, pacc, pmv, plv);
  dense2<<<dim3(256), dim3(256), 0, stream>>>(pacc, pmv, plv, d, WT, bias, out);
}